// Round 3
// baseline (562.561 us; speedup 1.0000x reference)
//
#include <hip/hip_runtime.h>
#include <float.h>

// Problem constants
#define NUM_Q 8
#define BN    8192      // B*N tokens
#define D     512
#define C     1024

// d_out layout (floats): [quantized_out | indices(as float) | losses]
#define QOUT_OFF 0
#define IDX_OFF  (BN * D)
#define LOSS_OFF (IDX_OFF + BN * NUM_Q)

// d_ws layout (bytes): top2 candidates [BN][16] u64, then e2 [NUM_Q*C] f32
#define TOP2_OFF_B 0
#define E2_OFF_B   (BN * 16 * 8)

typedef _Float16 f16x8 __attribute__((ext_vector_type(8)));
typedef float    f32x4 __attribute__((ext_vector_type(4)));

// Approx-GEMM tiling: 128 tokens x 128 codewords per block, 8 waves (64x32 tiles)
#define TM   128
#define TN   128
#define BK   64
#define LDKA 72          // padded f16 k-stride (144 B row) -> <=2-way banks
#define GTHREADS 512

__device__ __forceinline__ unsigned fkey(float f) {
    unsigned u = __float_as_uint(f);
    return (u & 0x80000000u) ? ~u : (u | 0x80000000u);
}
__device__ __forceinline__ unsigned long long u64min(unsigned long long a, unsigned long long b) {
    return a < b ? a : b;
}
__device__ __forceinline__ unsigned long long u64max(unsigned long long a, unsigned long long b) {
    return a > b ? a : b;
}
__device__ __forceinline__ unsigned long long shfl_xor_u64(unsigned long long v, int m) {
    int lo = __shfl_xor((int)(unsigned)v, m, 64);
    int hi = __shfl_xor((int)(unsigned)(v >> 32), m, 64);
    return ((unsigned long long)(unsigned)hi << 32) | (unsigned)lo;
}

// ---------------------------------------------------------------------------
// init: residual R (d_out quantized region) = x; zero loss slots
// ---------------------------------------------------------------------------
__global__ void rvq_init_kernel(const float* __restrict__ x, float* __restrict__ out) {
    int i = blockIdx.x * blockDim.x + threadIdx.x;
    const float4* x4 = (const float4*)x;
    float4* r4 = (float4*)(out + QOUT_OFF);
    const int n4 = BN * D / 4;
    for (int k = i; k < n4; k += gridDim.x * blockDim.x)
        r4[k] = x4[k];
    if (i < NUM_Q) out[LOSS_OFF + i] = 0.0f;
}

// ---------------------------------------------------------------------------
// e2: per-codeword squared norms, all layers. one wave per codeword row.
// ---------------------------------------------------------------------------
__global__ void rvq_e2_kernel(const float* __restrict__ cbs, float* __restrict__ e2ws) {
    const int row = blockIdx.x;
    const int lane = threadIdx.x;
    const float* p = cbs + (size_t)row * D + lane * 8;
    float4 a = *(const float4*)p;
    float4 b = *(const float4*)(p + 4);
    float ss = a.x*a.x + a.y*a.y + a.z*a.z + a.w*a.w
             + b.x*b.x + b.y*b.y + b.z*b.z + b.w*b.w;
#pragma unroll
    for (int off = 32; off >= 1; off >>= 1) ss += __shfl_xor(ss, off, 64);
    if (lane == 0) e2ws[row] = ss;
}

// ---------------------------------------------------------------------------
// approx pass: single f16 MFMA GEMM; emit per-token per-block top-2 candidates
// ---------------------------------------------------------------------------
__global__ __launch_bounds__(GTHREADS, 4) void rvq_approx_kernel(
    const float* __restrict__ cb,        // layer codebook [C][D]
    const float* __restrict__ R,         // residual [BN][D]
    const float* __restrict__ e2,        // layer e2 [C]
    unsigned long long* __restrict__ top2)  // [BN][16]
{
    __shared__ __align__(16) _Float16 As[TM][LDKA];
    __shared__ __align__(16) _Float16 Bs[TN][LDKA];
    __shared__ unsigned long long part[4][TM][2];

    const int tid  = threadIdx.x;
    const int lane = tid & 63;
    const int wv   = tid >> 6;
    const int wm   = wv & 1;     // token half (64)
    const int wn   = wv >> 1;    // codeword slice (32)
    const int lm   = lane & 15;
    const int lq   = lane >> 4;

    const int mg = blockIdx.x & 63;      // 8 n-blocks sharing an A tile adjacent
    const int nb = blockIdx.x >> 6;
    const int tok0 = mg * TM;
    const int cb0  = nb * TN;

    const int srow = tid >> 2;           // staging row 0..127
    const int sc   = tid & 3;            // 16-elem k-chunk

    const float* Ag = R  + (size_t)(tok0 + srow) * D + sc * 16;
    const float* Bg = cb + (size_t)(cb0  + srow) * D + sc * 16;

    f32x4 acc[4][2];
#pragma unroll
    for (int mt = 0; mt < 4; ++mt)
#pragma unroll
        for (int nt = 0; nt < 2; ++nt)
            acc[mt][nt] = (f32x4){0.f, 0.f, 0.f, 0.f};

    for (int kb = 0; kb < D / BK; ++kb) {
        const int kc = kb * BK;
        float4 a0 = *(const float4*)(Ag + kc);
        float4 a1 = *(const float4*)(Ag + kc + 4);
        float4 a2 = *(const float4*)(Ag + kc + 8);
        float4 a3 = *(const float4*)(Ag + kc + 12);
        float4 b0 = *(const float4*)(Bg + kc);
        float4 b1 = *(const float4*)(Bg + kc + 4);
        float4 b2 = *(const float4*)(Bg + kc + 8);
        float4 b3 = *(const float4*)(Bg + kc + 12);

        __syncthreads();   // previous iteration's LDS reads complete

        {
            float av[16] = {a0.x,a0.y,a0.z,a0.w, a1.x,a1.y,a1.z,a1.w,
                            a2.x,a2.y,a2.z,a2.w, a3.x,a3.y,a3.z,a3.w};
            f16x8 h0, h1;
#pragma unroll
            for (int i = 0; i < 8; ++i) { h0[i] = (_Float16)av[i]; h1[i] = (_Float16)av[8+i]; }
            *(f16x8*)&As[srow][sc * 16]     = h0;
            *(f16x8*)&As[srow][sc * 16 + 8] = h1;
        }
        {
            float bv[16] = {b0.x,b0.y,b0.z,b0.w, b1.x,b1.y,b1.z,b1.w,
                            b2.x,b2.y,b2.z,b2.w, b3.x,b3.y,b3.z,b3.w};
            f16x8 h0, h1;
#pragma unroll
            for (int i = 0; i < 8; ++i) { h0[i] = (_Float16)bv[i]; h1[i] = (_Float16)bv[8+i]; }
            *(f16x8*)&Bs[srow][sc * 16]     = h0;
            *(f16x8*)&Bs[srow][sc * 16 + 8] = h1;
        }
        __syncthreads();

#pragma unroll
        for (int kh = 0; kh < 2; ++kh) {
            f16x8 ah[4], bh[2];
#pragma unroll
            for (int mt = 0; mt < 4; ++mt)
                ah[mt] = *(const f16x8*)&As[wm * 64 + mt * 16 + lm][kh * 32 + lq * 8];
#pragma unroll
            for (int nt = 0; nt < 2; ++nt)
                bh[nt] = *(const f16x8*)&Bs[wn * 32 + nt * 16 + lm][kh * 32 + lq * 8];
#pragma unroll
            for (int mt = 0; mt < 4; ++mt)
#pragma unroll
                for (int nt = 0; nt < 2; ++nt)
                    acc[mt][nt] = __builtin_amdgcn_mfma_f32_16x16x32_f16(ah[mt], bh[nt], acc[mt][nt], 0, 0, 0);
        }
    }

    // ---- epilogue: approx scores, per-token top-2 within this block ----
    const int n0 = cb0 + wn * 32 + lm;
    const float e2v0 = e2[n0];
    const float e2v1 = e2[n0 + 16];

#pragma unroll
    for (int mt = 0; mt < 4; ++mt) {
#pragma unroll
        for (int r = 0; r < 4; ++r) {
            float s0 = e2v0 - 2.0f * acc[mt][0][r];
            float s1 = e2v1 - 2.0f * acc[mt][1][r];
            unsigned long long pa = ((unsigned long long)fkey(s0) << 32) | (unsigned)n0;
            unsigned long long pb = ((unsigned long long)fkey(s1) << 32) | (unsigned)(n0 + 16);
            unsigned long long lo = u64min(pa, pb);
            unsigned long long hi = u64max(pa, pb);
            // top-2 merge across the 16 lanes holding this token's columns
#pragma unroll
            for (int m = 1; m < 16; m <<= 1) {
                unsigned long long o1 = shfl_xor_u64(lo, m);
                unsigned long long o2 = shfl_xor_u64(hi, m);
                unsigned long long n1 = u64min(lo, o1);
                unsigned long long n2 = u64min(u64max(lo, o1), u64min(hi, o2));
                lo = n1; hi = n2;
            }
            if (lm == 0) {
                const int trow = wm * 64 + mt * 16 + lq * 4 + r;
                part[wn][trow][0] = lo;
                part[wn][trow][1] = hi;
            }
        }
    }
    __syncthreads();
    if (tid < TM) {
        unsigned long long lo = part[0][tid][0];
        unsigned long long hi = part[0][tid][1];
#pragma unroll
        for (int w = 1; w < 4; ++w) {
            unsigned long long q1 = part[w][tid][0];
            unsigned long long q2 = part[w][tid][1];
            unsigned long long n1 = u64min(lo, q1);
            unsigned long long n2 = u64min(u64max(lo, q1), u64min(hi, q2));
            lo = n1; hi = n2;
        }
        unsigned long long* dst = top2 + (size_t)(tok0 + tid) * 16 + nb * 2;
        dst[0] = lo;
        dst[1] = hi;
    }
}

// ---------------------------------------------------------------------------
// rescore + update: exact fp32 score of 16 candidates/token, pick min
// (first-index tie-break), residual -= codeword, loss partial, emit index.
// one wave per token, 8 tokens per block.
// ---------------------------------------------------------------------------
__global__ __launch_bounds__(512) void rvq_rescore_update_kernel(
    const float* __restrict__ cb, const float* __restrict__ e2,
    const unsigned long long* __restrict__ top2,
    float* __restrict__ out, int q)
{
    __shared__ float lsum[8];
    const int tid  = threadIdx.x;
    const int lane = tid & 63;
    const int w    = tid >> 6;
    const int tok  = blockIdx.x * 8 + w;

    float* rrow = out + QOUT_OFF + (size_t)tok * D + lane * 8;
    float4 r0 = *(const float4*)rrow;
    float4 r1 = *(const float4*)(rrow + 4);

    // lane i (i<16) holds candidate i's packed u64; we only need the index
    unsigned long long myc = top2[(size_t)tok * 16 + (lane & 15)];
    int myidx = (int)(unsigned)(myc & 0xFFFFFFFFull);

    unsigned long long best = ~0ull;
#pragma unroll 4
    for (int j = 0; j < 16; ++j) {
        int idx = __shfl(myidx, j, 64);
        const float* crow = cb + (size_t)idx * D + lane * 8;
        float4 c0 = *(const float4*)crow;
        float4 c1 = *(const float4*)(crow + 4);
        float p = r0.x*c0.x + r0.y*c0.y + r0.z*c0.z + r0.w*c0.w
                + r1.x*c1.x + r1.y*c1.y + r1.z*c1.z + r1.w*c1.w;
#pragma unroll
        for (int off = 32; off >= 1; off >>= 1) p += __shfl_xor(p, off, 64);
        float s = e2[idx] - 2.0f * p;
        unsigned long long key = ((unsigned long long)fkey(s) << 32) | (unsigned)idx;
        best = u64min(best, key);
    }

    const int bi = (int)(unsigned)(best & 0xFFFFFFFFull);
    const float* crow = cb + (size_t)bi * D + lane * 8;
    float4 c0 = *(const float4*)crow;
    float4 c1 = *(const float4*)(crow + 4);
    float4 n0 = make_float4(r0.x - c0.x, r0.y - c0.y, r0.z - c0.z, r0.w - c0.w);
    float4 n1 = make_float4(r1.x - c1.x, r1.y - c1.y, r1.z - c1.z, r1.w - c1.w);
    *(float4*)rrow = n0;
    *(float4*)(rrow + 4) = n1;
    float ss = n0.x*n0.x + n0.y*n0.y + n0.z*n0.z + n0.w*n0.w
             + n1.x*n1.x + n1.y*n1.y + n1.z*n1.z + n1.w*n1.w;
#pragma unroll
    for (int off = 32; off >= 1; off >>= 1) ss += __shfl_xor(ss, off, 64);
    if (lane == 0) {
        out[IDX_OFF + (size_t)tok * NUM_Q + q] = (float)bi;
        lsum[w] = ss;
    }
    __syncthreads();
    if (tid == 0) {
        float tot = 0.0f;
#pragma unroll
        for (int i = 0; i < 8; ++i) tot += lsum[i];
        atomicAdd(out + LOSS_OFF + q, tot);
    }
}

// ---------------------------------------------------------------------------
// finalize: quantized_out = x - residual_final (in place); scale losses
// ---------------------------------------------------------------------------
__global__ void rvq_finalize_kernel(const float* __restrict__ x, float* __restrict__ out) {
    int i = blockIdx.x * blockDim.x + threadIdx.x;
    const float4* x4 = (const float4*)x;
    float4* o4 = (float4*)(out + QOUT_OFF);
    const int n4 = BN * D / 4;
    for (int k = i; k < n4; k += gridDim.x * blockDim.x) {
        float4 xv = x4[k];
        float4 rv = o4[k];
        o4[k] = make_float4(xv.x - rv.x, xv.y - rv.y, xv.z - rv.z, xv.w - rv.w);
    }
    if (i < NUM_Q) out[LOSS_OFF + i] *= (1.0f / (float)(BN * D));
}

extern "C" void kernel_launch(void* const* d_in, const int* in_sizes, int n_in,
                              void* d_out, int out_size, void* d_ws, size_t ws_size,
                              hipStream_t stream) {
    const float* x   = (const float*)d_in[0];
    const float* cbs = (const float*)d_in[1];
    float* out = (float*)d_out;
    unsigned long long* top2 = (unsigned long long*)((char*)d_ws + TOP2_OFF_B);
    float* e2ws = (float*)((char*)d_ws + E2_OFF_B);

    hipLaunchKernelGGL(rvq_init_kernel, dim3(1024), dim3(256), 0, stream, x, out);
    hipLaunchKernelGGL(rvq_e2_kernel, dim3(NUM_Q * C), dim3(64), 0, stream, cbs, e2ws);

    float* R = out + QOUT_OFF;
    for (int q = 0; q < NUM_Q; ++q) {
        const float* cb_q = cbs + (size_t)q * C * D;
        hipLaunchKernelGGL(rvq_approx_kernel, dim3((BN / TM) * (C / TN)), dim3(GTHREADS), 0, stream,
                           cb_q, R, e2ws + (size_t)q * C, top2);
        hipLaunchKernelGGL(rvq_rescore_update_kernel, dim3(BN / 8), dim3(512), 0, stream,
                           cb_q, e2ws + (size_t)q * C, top2, out, q);
    }
    hipLaunchKernelGGL(rvq_finalize_kernel, dim3(1024), dim3(256), 0, stream, x, out);
}